// Round 1
// baseline (170.827 us; speedup 1.0000x reference)
//
#include <hip/hip_runtime.h>

// SDF volume rendering (NeuS/VolSDF-style), float32 in/out.
//
// Per ray (96 samples):
//   alpha_i = 1 - exp(-beta * sigmoid(-sdf_i * beta))
//   t_i     = 1 - alpha_i + 1e-10 = exp(-beta * sigmoid(-sdf_i*beta)) + 1e-10
//   trans_i = exclusive cumprod of t ;  w_i = alpha_i * trans_i
//   depth   = sum w_i * z_i ;  rgb_c = sum w_i * rgb_{i,c}
//
// R5: R4 was STILL latency-serialized -- VGPR_Count=20 cannot hold 5 live
// float4 (20 regs) + addresses, so the compiler provably issued the staging
// loads one-at-a-time (57us = 32 blocks/CU x ~4.3k cyc = 5 x ~900cy HBM
// latency, matches exactly). Root cause: branchy ternary pointers + clamped
// duplicate lanes made the LDS staging register-hungry, and the compiler
// chose minimal registers over ILP.
//
// Fix: drop LDS staging entirely. The 3-samples-per-lane compute layout is
// already CONTIGUOUS in global memory: lane l reads sdf[ray*96+3l..3l+2]
// (12B/lane, wave covers 768 contiguous bytes -> coalesced dwordx3) and
// rgb[ray*288+9l..9l+8] (36B/lane, contiguous). Five branch-free independent
// wide loads per thread, pinned above all consumers with sched_barrier(0).
// No barrier, no redundant clamp loads, no same-address store hotspot.
// Passthrough stores are the same registers written straight back out.
//
// Block = 256 threads = 8 rays (32 lanes/ray), zero LDS.

#define SDFR_NS 96

struct f3 { float x, y, z; };   // size 12, align 4 -> global_load_dwordx3

__global__ __launch_bounds__(256, 8) void sdf_render_kernel(
    const float* __restrict__ rgb,      // [N*96*3]
    const float* __restrict__ sdf,      // [N*96]
    const float* __restrict__ z_vals,   // [N*96]
    const int*   __restrict__ beta_p,   // scalar (int32, or f32 bit pattern)
    float* __restrict__ out_depth,      // [N]
    float* __restrict__ out_rgb,        // [N,3]
    float* __restrict__ out_sdf,        // [N*96]
    float* __restrict__ out_z,          // [N*96]
    int n_rays)
{
    const int tid = blockIdx.x * 256 + threadIdx.x;
    const int ray = tid >> 5;        // 32 lanes per ray, 2 rays per wave
    const int l   = tid & 31;        // lane l owns samples [3l, 3l+3)
    if (ray >= n_rays) return;

    const long sb = (long)ray * SDFR_NS + 3 * l;        // sdf/z float index
    const long rb = (long)ray * (SDFR_NS * 3) + 9 * l;  // rgb float index

    // ---- 5 independent, branch-free, coalesced wide loads ----
    const f3 sv = *(const f3*)(sdf    + sb);
    const f3 zv = *(const f3*)(z_vals + sb);
    const f3 ca = *(const f3*)(rgb + rb + 0);   // sample 3l   rgb
    const f3 cb = *(const f3*)(rgb + rb + 3);   // sample 3l+1 rgb
    const f3 cc = *(const f3*)(rgb + rb + 6);   // sample 3l+2 rgb
    __builtin_amdgcn_sched_barrier(0);  // pin all loads above any consumer

    // beta decode: small int is the value; huge magnitude is an f32 pattern
    int bi = *beta_p;
    float beta;
    if (bi > 1000000 || bi < -1000000) {
        union { int i; float f; } u; u.i = bi; beta = u.f;
    } else {
        beta = (float)bi;
    }

    // sigmoid(-s*beta) = 1/(1+exp(s*beta)); e = exp(-beta*sig)
    const float e0 = __expf(-beta * __builtin_amdgcn_rcpf(1.0f + __expf(sv.x * beta)));
    const float e1 = __expf(-beta * __builtin_amdgcn_rcpf(1.0f + __expf(sv.y * beta)));
    const float e2 = __expf(-beta * __builtin_amdgcn_rcpf(1.0f + __expf(sv.z * beta)));
    const float a0 = 1.0f - e0, t0 = e0 + 1e-10f;
    const float a1 = 1.0f - e1, t1 = e1 + 1e-10f;
    const float a2 = 1.0f - e2, t2 = e2 + 1e-10f;

    // ---- passthrough stores (bit-exact, from the loaded registers) ----
    *(f3*)(out_sdf + sb) = sv;
    *(f3*)(out_z   + sb) = zv;

    // ---- 32-lane exclusive prefix product of per-lane local product ----
    const float m = t0 * t1 * t2;
    float scan = m;
    #pragma unroll
    for (int d = 1; d < 32; d <<= 1) {
        float v = __shfl_up(scan, d, 32);
        if (l >= d) scan *= v;
    }
    float E = __shfl_up(scan, 1, 32);
    if (l == 0) E = 1.0f;

    const float w0 = a0 * E;
    const float w1 = a1 * E * t0;
    const float w2 = a2 * E * t0 * t1;

    float depth = w0 * zv.x + w1 * zv.y + w2 * zv.z;
    float r0    = w0 * ca.x + w1 * cb.x + w2 * cc.x;
    float r1    = w0 * ca.y + w1 * cb.y + w2 * cc.y;
    float r2    = w0 * ca.z + w1 * cb.z + w2 * cc.z;

    #pragma unroll
    for (int d = 16; d >= 1; d >>= 1) {
        depth += __shfl_xor(depth, d, 32);
        r0    += __shfl_xor(r0, d, 32);
        r1    += __shfl_xor(r1, d, 32);
        r2    += __shfl_xor(r2, d, 32);
    }

    if (l == 0) {
        out_depth[ray] = depth;
        f3 o; o.x = r0; o.y = r1; o.z = r2;
        *(f3*)(out_rgb + (long)ray * 3) = o;
    }
}

extern "C" void kernel_launch(void* const* d_in, const int* in_sizes, int n_in,
                              void* d_out, int out_size, void* d_ws, size_t ws_size,
                              hipStream_t stream) {
    (void)n_in; (void)d_ws; (void)ws_size; (void)out_size;

    const float* rgb    = (const float*)d_in[0];
    const float* sdf    = (const float*)d_in[1];
    const float* z      = (const float*)d_in[2];
    const int*   beta_p = (const int*)d_in[3];

    const int n_rays = in_sizes[1] / SDFR_NS;  // 65536

    // output layout (f32): depth[N] | rgb[N*3] | sdf[N*96] | z[N*96]
    float* out_depth = (float*)d_out;
    float* out_rgb   = out_depth + n_rays;
    float* out_sdf   = out_rgb   + (size_t)n_rays * 3;
    float* out_z     = out_sdf   + (size_t)n_rays * SDFR_NS;

    const long total_threads = (long)n_rays * 32;   // 32 lanes per ray
    const int  grid = (int)((total_threads + 255) / 256);  // 8192
    sdf_render_kernel<<<grid, 256, 0, stream>>>(
        rgb, sdf, z, beta_p, out_depth, out_rgb, out_sdf, out_z, n_rays);
}